// Round 1
// baseline (125.469 us; speedup 1.0000x reference)
//
#include <hip/hip_runtime.h>
#include <math.h>

#define Nn 8192
#define Dd 256
#define Kk 32
#define RPB 16   // rows per block in main kernel

// ws float layout:
// [0,      8192)  u4T : w transposed, [d/4][k][4]
// [8192,  16384)  v4T : w*b transposed, same layout
// [16384, 24576)  G[k][d]
// [24576, 32768)  H[k][d]
// [32768, 32800)  s[k]

__global__ __launch_bounds__(256) void prep_kernel(const float* __restrict__ w,
                                                   const float* __restrict__ b,
                                                   float* __restrict__ ws) {
    int k = blockIdx.x, d = threadIdx.x;
    float wv = w[k * Dd + d];
    float bv = b[k * Dd + d];
    int gi = ((d >> 2) * Kk + k) * 4 + (d & 3);
    ws[gi]        = wv;        // u4T
    ws[8192 + gi] = wv * bv;   // v4T
    ws[16384 + k * Dd + d] = 0.f;  // G
    ws[24576 + k * Dd + d] = 0.f;  // H
    if (k == 0 && d < Kk) ws[32768 + d] = 0.f;  // s
}

__global__ __launch_bounds__(256) void main_kernel(const float* __restrict__ x,
                                                   float* __restrict__ ws) {
    const float* u4T = ws;
    const float* v4T = ws + 8192;
    float* G = ws + 16384;
    float* H = ws + 24576;
    float* S = ws + 32768;

    __shared__ __align__(16) float uS[8192];      // 32 KB staged w (transposed)
    __shared__ __align__(16) float gam[4][32];    // gamma for 4 rows in flight

    int tid = threadIdx.x;

    // stage u4T into LDS (coalesced float4)
    {
        const float4* src = (const float4*)u4T;
        float4* dst = (float4*)uS;
        #pragma unroll
        for (int i = 0; i < 8; ++i) dst[tid + 256 * i] = src[tid + 256 * i];
    }
    __syncthreads();

    int lane = tid & 63;
    int wave = tid >> 6;
    int k = lane & 31;
    int h = lane >> 5;

    float accg[32], acch[32];
    #pragma unroll
    for (int i = 0; i < 32; ++i) { accg[i] = 0.f; acch[i] = 0.f; }
    float sacc = 0.f;

    int base = blockIdx.x * RPB;

    for (int it = 0; it < RPB / 4; ++it) {
        int rowbase = base + it * 4;

        // ---- gamma phase: one wave per row ----
        {
            int row = rowbase + wave;
            const float4* xr  = (const float4*)(x + (size_t)row * Dd);
            const float4* uS4 = (const float4*)uS;
            const float4* v4  = (const float4*)v4T;
            float a0 = 0.f, a1 = 0.f, a2 = 0.f, a3 = 0.f;
            int bidx = h * 32;  // float4 index base for this half
            #pragma unroll 8
            for (int i = 0; i < 32; ++i) {
                float4 xv = xr[bidx + i];          // broadcast within half-wave
                int gi = (bidx + i) * 32 + k;
                float4 uv = uS4[gi];               // LDS, conflict-free
                float4 vv = v4[gi];                // global, L1/L2 resident
                float y0 = fmaf(uv.x, xv.x, vv.x);
                float y1 = fmaf(uv.y, xv.y, vv.y);
                float y2 = fmaf(uv.z, xv.z, vv.z);
                float y3 = fmaf(uv.w, xv.w, vv.w);
                a0 = fmaf(y0, y0, a0);
                a1 = fmaf(y1, y1, a1);
                a2 = fmaf(y2, y2, a2);
                a3 = fmaf(y3, y3, a3);
            }
            float ss = (a0 + a1) + (a2 + a3);
            ss += __shfl_xor(ss, 32);              // combine the two d-halves
            float y4v = -0.5f * ss;
            float m = y4v;
            #pragma unroll
            for (int o = 16; o >= 1; o >>= 1) m = fmaxf(m, __shfl_xor(m, o));
            float e = __expf(y4v - m);
            float se = e;
            #pragma unroll
            for (int o = 16; o >= 1; o >>= 1) se += __shfl_xor(se, o);
            float g = e / se;
            if (h == 0) gam[wave][k] = g;
        }
        __syncthreads();

        // ---- accumulate phase: thread t owns column d = tid ----
        #pragma unroll
        for (int r = 0; r < 4; ++r) {
            float xv = x[(size_t)(rowbase + r) * Dd + tid];
            float xx = xv * xv;
            const float4* gr = (const float4*)(&gam[r][0]);
            #pragma unroll
            for (int q = 0; q < 8; ++q) {
                float4 gv = gr[q];                 // LDS broadcast
                accg[4*q+0] = fmaf(gv.x, xv, accg[4*q+0]);
                acch[4*q+0] = fmaf(gv.x, xx, acch[4*q+0]);
                accg[4*q+1] = fmaf(gv.y, xv, accg[4*q+1]);
                acch[4*q+1] = fmaf(gv.y, xx, acch[4*q+1]);
                accg[4*q+2] = fmaf(gv.z, xv, accg[4*q+2]);
                acch[4*q+2] = fmaf(gv.z, xx, acch[4*q+2]);
                accg[4*q+3] = fmaf(gv.w, xv, accg[4*q+3]);
                acch[4*q+3] = fmaf(gv.w, xx, acch[4*q+3]);
            }
        }
        if (tid < 32) sacc += gam[0][tid] + gam[1][tid] + gam[2][tid] + gam[3][tid];
        __syncthreads();
    }

    #pragma unroll
    for (int kk = 0; kk < 32; ++kk) {
        atomicAdd(&G[kk * Dd + tid], accg[kk]);
        atomicAdd(&H[kk * Dd + tid], acch[kk]);
    }
    if (tid < 32) atomicAdd(&S[tid], sacc);
}

__global__ __launch_bounds__(256) void epi_kernel(const float* __restrict__ w,
                                                  const float* __restrict__ b,
                                                  const float* __restrict__ ws,
                                                  float* __restrict__ out) {
    int k = blockIdx.x, d = threadIdx.x;
    int idx = k * Dd + d;
    float Gv = ws[16384 + idx];
    float Hv = ws[24576 + idx];
    float sv = ws[32768 + k];
    float wv = w[idx], bv = b[idx];
    const float invN = 1.0f / 8192.0f;
    const float c2 = 0.70710678118654752440f * invN;  // 1/(sqrt(2)*N)
    float mu = wv * (Gv + bv * sv) * invN;
    float w2 = wv * wv;
    float sg = (w2 * (Hv + 2.0f * bv * Gv + bv * bv * sv) - sv) * c2;
    out[idx] = sg;            // sigma_part
    out[Kk * Dd + idx] = mu;  // mu_part
}

extern "C" void kernel_launch(void* const* d_in, const int* in_sizes, int n_in,
                              void* d_out, int out_size, void* d_ws, size_t ws_size,
                              hipStream_t stream) {
    const float* x = (const float*)d_in[0];
    const float* w = (const float*)d_in[1];
    const float* b = (const float*)d_in[2];
    float* out = (float*)d_out;
    float* ws = (float*)d_ws;

    hipLaunchKernelGGL(prep_kernel, dim3(Kk), dim3(256), 0, stream, w, b, ws);
    hipLaunchKernelGGL(main_kernel, dim3(Nn / RPB), dim3(256), 0, stream, x, ws);
    hipLaunchKernelGGL(epi_kernel, dim3(Kk), dim3(256), 0, stream, w, b, ws, out);
}